// Round 1
// baseline (1721.012 us; speedup 1.0000x reference)
//
#include <hip/hip_runtime.h>
#include <hip/hip_bf16.h>
#include <math.h>

#define N_NODES 50000
#define IN_DIM  256
#define LATENT  128
#define FINALD  64
#define NGRAPH  2
#define NEDGE   1000000
#define BATCHSZ 16384

// ---------------------------------------------------------------------------
// Fused GEMM:  C[N,M] = post( act( A1@W1 (+ A2@W2) (+ bias) ) (+ addm) )
// act: 0 = none, 1 = elu.  addm is added AFTER activation.
// Tiling: 64x64 block tile, BK=16, 256 threads, 4x4 micro-tile/thread.
// A staged transposed in LDS so inner loop is 2x ds_read_b128 per 16 FMAs.
// ---------------------------------------------------------------------------
template<int BM, int BN, int BK>
__global__ __launch_bounds__(256)
void gemm_fused(const float* __restrict__ A1, const float* __restrict__ W1, int K1,
                const float* __restrict__ A2, const float* __restrict__ W2, int K2,
                const float* __restrict__ bias, const float* __restrict__ addm,
                float* __restrict__ C, int N, int M, int act)
{
    __shared__ float At[BK][BM + 4];
    __shared__ float Wt[BK][BN + 4];

    const int tid = threadIdx.x;
    const int rowBase = blockIdx.x * BM;
    const int colBase = blockIdx.y * BN;
    const int tx = tid & 15;        // micro col group
    const int ty = tid >> 4;        // micro row group
    const int lrow = tid >> 2;      // A-stage row within tile (0..63)
    const int lkq  = (tid & 3) * 4; // A-stage k offset (0,4,8,12)
    const int wkk  = tid >> 4;      // W-stage k row (0..15)
    const int wcp  = (tid & 15) * 4;// W-stage col offset

    float acc[4][4] = {};

    const float* Aptr = A1;
    const float* Wptr = W1;
    int K = K1;

    for (int pass = 0; pass < 2; ++pass) {
        if (pass == 1) {
            if (A2 == nullptr) break;
            Aptr = A2; Wptr = W2; K = K2;
        }
        for (int k0 = 0; k0 < K; k0 += BK) {
            // stage A tile (transposed)
            {
                int grow = rowBase + lrow;
                float4 av = make_float4(0.f, 0.f, 0.f, 0.f);
                if (grow < N)
                    av = *(const float4*)(Aptr + (size_t)grow * K + k0 + lkq);
                At[lkq + 0][lrow] = av.x;
                At[lkq + 1][lrow] = av.y;
                At[lkq + 2][lrow] = av.z;
                At[lkq + 3][lrow] = av.w;
            }
            // stage W tile
            {
                float4 wv = *(const float4*)(Wptr + (size_t)(k0 + wkk) * M + colBase + wcp);
                *(float4*)&Wt[wkk][wcp] = wv;
            }
            __syncthreads();
            #pragma unroll
            for (int kk = 0; kk < BK; ++kk) {
                float4 a4 = *(const float4*)&At[kk][ty * 4];
                float4 w4 = *(const float4*)&Wt[kk][tx * 4];
                float ar[4] = {a4.x, a4.y, a4.z, a4.w};
                float wr[4] = {w4.x, w4.y, w4.z, w4.w};
                #pragma unroll
                for (int i = 0; i < 4; ++i)
                    #pragma unroll
                    for (int j = 0; j < 4; ++j)
                        acc[i][j] += ar[i] * wr[j];
            }
            __syncthreads();
        }
    }

    // epilogue
    #pragma unroll
    for (int i = 0; i < 4; ++i) {
        int r = rowBase + ty * 4 + i;
        if (r >= N) continue;
        #pragma unroll
        for (int j = 0; j < 4; ++j) {
            int c = colBase + tx * 4 + j;
            float v = acc[i][j];
            if (bias) v += bias[c];
            if (act == 1) v = v > 0.f ? v : (__expf(v) - 1.f);
            if (addm) v += addm[(size_t)r * M + c];
            C[(size_t)r * M + c] = v;
        }
    }
}

// ---------------------------------------------------------------------------
// alpha_self / alpha_nb : per-row dot of H1 with two vectors. Wave per row.
// ---------------------------------------------------------------------------
__global__ __launch_bounds__(256)
void rowdots(const float* __restrict__ H1, const float* __restrict__ a1,
             const float* __restrict__ a2,
             float* __restrict__ o1, float* __restrict__ o2, int n)
{
    int lane = threadIdx.x & 63, wid = threadIdx.x >> 6;
    int row = blockIdx.x * 4 + wid;
    if (row >= n) return;
    float2 h = *(const float2*)(H1 + (size_t)row * LATENT + lane * 2);
    float2 x = *(const float2*)(a1 + lane * 2);
    float2 y = *(const float2*)(a2 + lane * 2);
    float d1 = h.x * x.x + h.y * x.y;
    float d2 = h.x * y.x + h.y * y.y;
    for (int o = 32; o; o >>= 1) {
        d1 += __shfl_xor(d1, o);
        d2 += __shfl_xor(d2, o);
    }
    if (lane == 0) { o1[row] = d1; o2[row] = d2; }
}

// ---------------------------------------------------------------------------
// CSR build: histogram, exclusive scan (single block), counting-sort fill
// ---------------------------------------------------------------------------
__global__ void edge_count(const int* __restrict__ dst, int* __restrict__ cnt, int e)
{
    int i = blockIdx.x * blockDim.x + threadIdx.x;
    if (i < e) atomicAdd(&cnt[dst[i]], 1);
}

__global__ __launch_bounds__(1024)
void scan_offsets(const int* __restrict__ cnt, int* __restrict__ offs,
                  int* __restrict__ cursor, int n)
{
    __shared__ int sm[2][1024];
    int tid = threadIdx.x;
    int chunk = (n + 1023) >> 10;
    int lo = tid * chunk, hi = min(lo + chunk, n);
    int s = 0;
    for (int i = lo; i < hi; ++i) s += cnt[i];
    sm[0][tid] = s;
    __syncthreads();
    int pi = 0;
    for (int o = 1; o < 1024; o <<= 1) {
        int v = sm[pi][tid];
        if (tid >= o) v += sm[pi][tid - o];
        sm[pi ^ 1][tid] = v;
        __syncthreads();
        pi ^= 1;
    }
    int base = sm[pi][tid] - s;   // exclusive
    for (int i = lo; i < hi; ++i) {
        offs[i] = base; cursor[i] = base;
        base += cnt[i];
    }
    if (lo < n && hi == n) offs[n] = base;
}

__global__ void edge_fill(const int* __restrict__ src, const int* __restrict__ dst,
                          int* __restrict__ cursor, int* __restrict__ csr_src, int e)
{
    int i = blockIdx.x * blockDim.x + threadIdx.x;
    if (i < e) {
        int d = dst[i];
        int p = atomicAdd(&cursor[d], 1);
        csr_src[p] = src[i];
    }
}

// ---------------------------------------------------------------------------
// GAT aggregation: one wave per dst node. Segment softmax in-wave (shfl),
// then serial edge loop gathering H1[src] rows (64 lanes x float2).
// ---------------------------------------------------------------------------
__global__ __launch_bounds__(256)
void gat_aggregate(const float* __restrict__ H1, const float* __restrict__ asf,
                   const float* __restrict__ anb,
                   const int* __restrict__ offs, const int* __restrict__ csr,
                   const float* __restrict__ omega, int g, int init,
                   float* __restrict__ H2, int n)
{
    int lane = threadIdx.x & 63, wid = threadIdx.x >> 6;
    int d = blockIdx.x * 4 + wid;
    if (d >= n) return;
    int beg = offs[d], end = offs[d + 1];
    float om = omega[g];
    float ad = asf[d];

    float m = -INFINITY;
    for (int e = beg + lane; e < end; e += 64) {
        float sc = ad + anb[csr[e]];
        sc = sc > 0.f ? sc : 0.2f * sc;
        m = fmaxf(m, sc);
    }
    for (int o = 32; o; o >>= 1) m = fmaxf(m, __shfl_xor(m, o));

    float ss = 0.f;
    for (int e = beg + lane; e < end; e += 64) {
        float sc = ad + anb[csr[e]];
        sc = sc > 0.f ? sc : 0.2f * sc;
        ss += __expf(sc - m);
    }
    for (int o = 32; o; o >>= 1) ss += __shfl_xor(ss, o);
    float inv = 1.f / (ss + 1e-16f);

    int c = lane * 2;
    float acc0 = 0.f, acc1 = 0.f;
    for (int e = beg; e < end; ++e) {
        int s = csr[e];
        float sc = ad + anb[s];
        sc = sc > 0.f ? sc : 0.2f * sc;
        float w = __expf(sc - m) * inv;
        float2 h = *(const float2*)(H1 + (size_t)s * LATENT + c);
        acc0 += w * h.x;
        acc1 += w * h.y;
    }
    float2* out = (float2*)(H2 + (size_t)d * LATENT + c);
    if (init) {
        *out = make_float2(om * acc0, om * acc1);
    } else {
        float2 p = *out;
        *out = make_float2(p.x + om * acc0, p.y + om * acc1);
    }
}

// ---------------------------------------------------------------------------
// Final prediction: wave per batch element (FINALD == 64 lanes)
// ---------------------------------------------------------------------------
__global__ __launch_bounds__(256)
void predict(const int* __restrict__ uid, const int* __restrict__ iid,
             const float* __restrict__ U, const float* __restrict__ B,
             const float* __restrict__ bu, const float* __restrict__ bb,
             const float* __restrict__ bx, float* __restrict__ out, int batch)
{
    int lane = threadIdx.x & 63, wid = threadIdx.x >> 6;
    int b = blockIdx.x * 4 + wid;
    if (b >= batch) return;
    int u = uid[b], it = iid[b];
    float p = U[(size_t)u * FINALD + lane] * B[(size_t)it * FINALD + lane];
    for (int o = 32; o; o >>= 1) p += __shfl_xor(p, o);
    if (lane == 0) {
        float raw = p + bu[u] + bb[it] + bx[0];
        out[b] = 4.f * (1.f / (1.f + __expf(-raw))) + 1.f;
    }
}

// ---------------------------------------------------------------------------
extern "C" void kernel_launch(void* const* d_in, const int* in_sizes, int n_in,
                              void* d_out, int out_size, void* d_ws, size_t ws_size,
                              hipStream_t stream)
{
    const int N = N_NODES;

    // workspace layout (floats)
    float* ws    = (float*)d_ws;
    float* H1    = ws;                                   // N*LATENT (reused as H3)
    float* H2    = H1 + (size_t)N * LATENT;              // N*LATENT
    float* U_all = H2 + (size_t)N * LATENT;              // N*FINALD
    float* B_all = U_all + (size_t)N * FINALD;           // N*FINALD
    float* asf   = B_all + (size_t)N * FINALD;           // N
    float* anb   = asf + N;                              // N
    int*   cnt    = (int*)(anb + N);                     // N
    int*   offs   = cnt + N;                             // N+1
    int*   cursor = offs + N + 1;                        // N
    int*   csr    = cursor + N;                          // NEDGE
    float* H3    = H1;                                   // overlay

    dim3 gL((N + 63) / 64, LATENT / 64);  // 782 x 2
    dim3 gF((N + 63) / 64, FINALD / 64);  // 782 x 1
    const int eBlocks = (NEDGE + 255) / 256;

    for (int side = 0; side < 2; ++side) {
        const float* S   = (const float*)d_in[side == 0 ? 2 : 3];
        const int*   edg = (const int*)  d_in[side == 0 ? 4 : 5];
        const float* W1  = (const float*)d_in[side == 0 ? 6 : 10];
        const float* avs = (const float*)d_in[side == 0 ? 7 : 11];
        const float* avn = (const float*)d_in[side == 0 ? 8 : 12];
        const float* om  = (const float*)d_in[side == 0 ? 9 : 13];
        const float* W2a = (const float*)d_in[side == 0 ? 14 : 17];
        const float* W2s = (const float*)d_in[side == 0 ? 15 : 18];
        const float* b2  = (const float*)d_in[side == 0 ? 16 : 19];
        const float* W3  = (const float*)d_in[side == 0 ? 20 : 21];
        const float* H4  = (const float*)d_in[side == 0 ? 22 : 23];
        float* OUT = side == 0 ? U_all : B_all;

        // H1 = S @ W1
        gemm_fused<64, 64, 16><<<gL, 256, 0, stream>>>(
            S, W1, IN_DIM, nullptr, nullptr, 0, nullptr, nullptr,
            H1, N, LATENT, 0);

        // alpha_self / alpha_nb
        rowdots<<<N / 4, 256, 0, stream>>>(H1, avs, avn, asf, anb, N);

        for (int g = 0; g < NGRAPH; ++g) {
            const int* esrc = edg + (size_t)g * 2 * NEDGE;
            const int* edst = esrc + NEDGE;
            hipMemsetAsync(cnt, 0, (size_t)N * sizeof(int), stream);
            edge_count<<<eBlocks, 256, 0, stream>>>(edst, cnt, NEDGE);
            scan_offsets<<<1, 1024, 0, stream>>>(cnt, offs, cursor, N);
            edge_fill<<<eBlocks, 256, 0, stream>>>(esrc, edst, cursor, csr, NEDGE);
            gat_aggregate<<<N / 4, 256, 0, stream>>>(
                H1, asf, anb, offs, csr, om, g, g == 0 ? 1 : 0, H2, N);
        }

        // H3 = elu(H2@W2a + S@W2s + b2)   (H3 overlays H1; H1 no longer needed)
        gemm_fused<64, 64, 16><<<gL, 256, 0, stream>>>(
            H2, W2a, LATENT, S, W2s, IN_DIM, b2, nullptr,
            H3, N, LATENT, 1);

        // OUT = elu(H3@W3) + H4
        gemm_fused<64, 64, 16><<<gF, 256, 0, stream>>>(
            H3, W3, LATENT, nullptr, nullptr, 0, nullptr, H4,
            OUT, N, FINALD, 1);
    }

    predict<<<BATCHSZ / 4, 256, 0, stream>>>(
        (const int*)d_in[0], (const int*)d_in[1], U_all, B_all,
        (const float*)d_in[24], (const float*)d_in[25], (const float*)d_in[26],
        (float*)d_out, BATCHSZ);
}

// Round 2
// 1326.994 us; speedup vs baseline: 1.2969x; 1.2969x over previous
//
#include <hip/hip_runtime.h>
#include <math.h>

#define N_NODES 50000
#define IN_DIM  256
#define LATENT  128
#define FINALD  64
#define NGRAPH  2
#define NEDGE   1000000
#define BATCHSZ 16384

typedef __attribute__((ext_vector_type(8))) short bf16x8;
typedef __attribute__((ext_vector_type(4))) float f32x4;
typedef __attribute__((ext_vector_type(8))) unsigned short u16x8;
typedef __attribute__((ext_vector_type(4))) unsigned short u16x4;

__device__ inline unsigned short f2bf(float x) {
    unsigned int u = __float_as_uint(x);
    u = (u + 0x7fffu + ((u >> 16) & 1u)) >> 16;
    return (unsigned short)u;
}
__device__ inline float bf2f(unsigned short h) {
    return __uint_as_float(((unsigned int)h) << 16);
}

// ---------------------------------------------------------------------------
// Split-precision bf16 MFMA GEMM.
// C[M,Ncols] = post( act( A1@B1 (+ A2@B2) (+bias) ) (+addm) )
// A@B computed as Ah@Bh + Ah@Bl + Al@Bh  (hi/lo bf16 split, fp32-grade).
// 64x64 tile, BK=64, 256 thr (4 waves, 2x2), mfma_f32_16x16x32_bf16.
// LDS tiles [64 rows][64 k] bf16, XOR-swizzled in 16B chunks (T2).
// ---------------------------------------------------------------------------
#define GBM 64
#define GBK 64

__device__ inline int swz(int r, int k) {
    return r * GBK + ((((k >> 3) ^ (r & 7)) << 3) | (k & 7));
}

__global__ __launch_bounds__(256)
void gemm_mfma(const float* __restrict__ A1, const float* __restrict__ B1, int K1,
               const float* __restrict__ A2, const float* __restrict__ B2, int K2,
               const float* __restrict__ bias, const float* __restrict__ addm,
               void* __restrict__ Cout, int M, int Ncols, int act, int out_bf16)
{
    __shared__ unsigned short AhS[GBM * GBK];
    __shared__ unsigned short AlS[GBM * GBK];
    __shared__ unsigned short BhS[GBM * GBK];
    __shared__ unsigned short BlS[GBM * GBK];

    const int tid = threadIdx.x;
    const int rowBase = blockIdx.x * GBM;
    const int colBase = blockIdx.y * GBM;
    const int wave = tid >> 6, lane = tid & 63;
    const int wr = wave >> 1, wc = wave & 1;
    const int sl = lane & 15, lg = lane >> 4;

    f32x4 acc[2][2] = {};

    const float* Ap = A1;
    const float* Bp = B1;
    int K = K1;

    for (int pass = 0; pass < 2; ++pass) {
        if (pass == 1) { if (!A2) break; Ap = A2; Bp = B2; K = K2; }
        for (int k0 = 0; k0 < K; k0 += GBK) {
            __syncthreads();   // previous-iter LDS reads done before overwrite
            // ---- stage A tile: 64 rows x 64 k
            #pragma unroll
            for (int p = 0; p < 4; ++p) {
                int q = p * 256 + tid;
                int row = q >> 4;
                int kq = (q & 15) << 2;
                int grow = rowBase + row;
                float4 v = make_float4(0.f, 0.f, 0.f, 0.f);
                if (grow < M) v = *(const float4*)(Ap + (size_t)grow * K + k0 + kq);
                unsigned short h0 = f2bf(v.x), h1 = f2bf(v.y), h2 = f2bf(v.z), h3 = f2bf(v.w);
                u16x4 hv = {h0, h1, h2, h3};
                u16x4 lv = {f2bf(v.x - bf2f(h0)), f2bf(v.y - bf2f(h1)),
                            f2bf(v.z - bf2f(h2)), f2bf(v.w - bf2f(h3))};
                int off = swz(row, kq);
                *(u16x4*)&AhS[off] = hv;
                *(u16x4*)&AlS[off] = lv;
            }
            // ---- stage B tile transposed: row n holds k-contiguous
            {
                int n = tid & 63;
                int kq = (tid >> 6) << 4;   // 0,16,32,48
                #pragma unroll
                for (int c = 0; c < 2; ++c) {
                    u16x8 hv, lv;
                    #pragma unroll
                    for (int j = 0; j < 8; ++j) {
                        float x = Bp[(size_t)(k0 + kq + c * 8 + j) * Ncols + colBase + n];
                        unsigned short h = f2bf(x);
                        hv[j] = h;
                        lv[j] = f2bf(x - bf2f(h));
                    }
                    int off = swz(n, kq + c * 8);
                    *(u16x8*)&BhS[off] = hv;
                    *(u16x8*)&BlS[off] = lv;
                }
            }
            __syncthreads();
            // ---- compute: 2 k-subtiles of 32
            #pragma unroll
            for (int ks = 0; ks < 2; ++ks) {
                int kof = ks * 32 + lg * 8;
                bf16x8 ah[2], al[2], bh[2], bl[2];
                #pragma unroll
                for (int f = 0; f < 2; ++f) {
                    int m = wr * 32 + f * 16 + sl;
                    int oa = swz(m, kof);
                    ah[f] = *(const bf16x8*)&AhS[oa];
                    al[f] = *(const bf16x8*)&AlS[oa];
                    int n = wc * 32 + f * 16 + sl;
                    int ob = swz(n, kof);
                    bh[f] = *(const bf16x8*)&BhS[ob];
                    bl[f] = *(const bf16x8*)&BlS[ob];
                }
                #pragma unroll
                for (int fm = 0; fm < 2; ++fm)
                    #pragma unroll
                    for (int fn = 0; fn < 2; ++fn) {
                        acc[fm][fn] = __builtin_amdgcn_mfma_f32_16x16x32_bf16(ah[fm], bh[fn], acc[fm][fn], 0, 0, 0);
                        acc[fm][fn] = __builtin_amdgcn_mfma_f32_16x16x32_bf16(ah[fm], bl[fn], acc[fm][fn], 0, 0, 0);
                        acc[fm][fn] = __builtin_amdgcn_mfma_f32_16x16x32_bf16(al[fm], bh[fn], acc[fm][fn], 0, 0, 0);
                    }
            }
        }
    }

    // ---- epilogue: C row = (lane>>4)*4 + reg, col = lane&15 (m89 layout)
    #pragma unroll
    for (int fm = 0; fm < 2; ++fm)
        #pragma unroll
        for (int r = 0; r < 4; ++r) {
            int row = rowBase + wr * 32 + fm * 16 + lg * 4 + r;
            if (row >= M) continue;
            #pragma unroll
            for (int fn = 0; fn < 2; ++fn) {
                int col = colBase + wc * 32 + fn * 16 + sl;
                float v = acc[fm][fn][r];
                if (bias) v += bias[col];
                if (act) v = v > 0.f ? v : (__expf(v) - 1.f);
                if (addm) v += addm[(size_t)row * Ncols + col];
                if (out_bf16)
                    ((unsigned short*)Cout)[(size_t)row * Ncols + col] = f2bf(v);
                else
                    ((float*)Cout)[(size_t)row * Ncols + col] = v;
            }
        }
}

// ---------------------------------------------------------------------------
// alpha_self / alpha_nb from bf16 H1. Wave per row.
// ---------------------------------------------------------------------------
__global__ __launch_bounds__(256)
void rowdots(const unsigned short* __restrict__ H1b, const float* __restrict__ a1,
             const float* __restrict__ a2,
             float* __restrict__ o1, float* __restrict__ o2, int n)
{
    int lane = threadIdx.x & 63, wid = threadIdx.x >> 6;
    int row = blockIdx.x * 4 + wid;
    if (row >= n) return;
    unsigned int hv = *(const unsigned int*)(H1b + (size_t)row * LATENT + lane * 2);
    float h0 = bf2f((unsigned short)(hv & 0xffffu));
    float h1 = bf2f((unsigned short)(hv >> 16));
    float2 x = *(const float2*)(a1 + lane * 2);
    float2 y = *(const float2*)(a2 + lane * 2);
    float d1 = h0 * x.x + h1 * x.y;
    float d2 = h0 * y.x + h1 * y.y;
    #pragma unroll
    for (int o = 32; o; o >>= 1) {
        d1 += __shfl_xor(d1, o);
        d2 += __shfl_xor(d2, o);
    }
    if (lane == 0) { o1[row] = d1; o2[row] = d2; }
}

// ---------------------------------------------------------------------------
// CSR build: histogram, exclusive scan (single block), counting-sort fill
// ---------------------------------------------------------------------------
__global__ void edge_count(const int* __restrict__ dst, int* __restrict__ cnt, int e)
{
    int i = blockIdx.x * blockDim.x + threadIdx.x;
    if (i < e) atomicAdd(&cnt[dst[i]], 1);
}

__global__ __launch_bounds__(1024)
void scan_offsets(const int* __restrict__ cnt, int* __restrict__ offs,
                  int* __restrict__ cursor, int n)
{
    __shared__ int sm[2][1024];
    int tid = threadIdx.x;
    int chunk = (n + 1023) >> 10;
    int lo = tid * chunk, hi = min(lo + chunk, n);
    int s = 0;
    for (int i = lo; i < hi; ++i) s += cnt[i];
    sm[0][tid] = s;
    __syncthreads();
    int pi = 0;
    for (int o = 1; o < 1024; o <<= 1) {
        int v = sm[pi][tid];
        if (tid >= o) v += sm[pi][tid - o];
        sm[pi ^ 1][tid] = v;
        __syncthreads();
        pi ^= 1;
    }
    int base = sm[pi][tid] - s;   // exclusive
    for (int i = lo; i < hi; ++i) {
        offs[i] = base; cursor[i] = base;
        base += cnt[i];
    }
    if (lo < n && hi == n) offs[n] = base;
}

__global__ void edge_fill(const int* __restrict__ src, const int* __restrict__ dst,
                          int* __restrict__ cursor, int* __restrict__ csr_src, int e)
{
    int i = blockIdx.x * blockDim.x + threadIdx.x;
    if (i < e) {
        int d = dst[i];
        int p = atomicAdd(&cursor[d], 1);
        csr_src[p] = src[i];
    }
}

// ---------------------------------------------------------------------------
// GAT aggregation: wave per dst. In-wave softmax; 4 edges in flight
// (4 x 16-lane groups, 16B u16x8 gather per lane), fp32 accumulate.
// ---------------------------------------------------------------------------
__global__ __launch_bounds__(256)
void gat_aggregate(const unsigned short* __restrict__ H1b, const float* __restrict__ asf,
                   const float* __restrict__ anb,
                   const int* __restrict__ offs, const int* __restrict__ csr,
                   const float* __restrict__ omega, int g, int init,
                   float* __restrict__ H2, int n)
{
    int lane = threadIdx.x & 63, wid = threadIdx.x >> 6;
    int d = blockIdx.x * 4 + wid;
    if (d >= n) return;
    int beg = offs[d], end = offs[d + 1];
    float om = omega[g];
    float ad = asf[d];

    float m = -INFINITY;
    for (int e = beg + lane; e < end; e += 64) {
        float sc = ad + anb[csr[e]];
        sc = sc > 0.f ? sc : 0.2f * sc;
        m = fmaxf(m, sc);
    }
    #pragma unroll
    for (int o = 32; o; o >>= 1) m = fmaxf(m, __shfl_xor(m, o));

    float ss = 0.f;
    for (int e = beg + lane; e < end; e += 64) {
        float sc = ad + anb[csr[e]];
        sc = sc > 0.f ? sc : 0.2f * sc;
        ss += __expf(sc - m);
    }
    #pragma unroll
    for (int o = 32; o; o >>= 1) ss += __shfl_xor(ss, o);
    float wsc = om / (ss + 1e-16f);

    int sub = lane >> 4, sl = lane & 15;
    float acc[8] = {};
    for (int e = beg + sub; e < end; e += 4) {
        int s = csr[e];
        float sc = ad + anb[s];
        sc = sc > 0.f ? sc : 0.2f * sc;
        float w = __expf(sc - m) * wsc;
        u16x8 h = *(const u16x8*)(H1b + (size_t)s * LATENT + sl * 8);
        #pragma unroll
        for (int j = 0; j < 8; ++j) acc[j] += w * bf2f(h[j]);
    }
    #pragma unroll
    for (int j = 0; j < 8; ++j) {
        acc[j] += __shfl_xor(acc[j], 32);
        acc[j] += __shfl_xor(acc[j], 16);
    }
    if (sub == 0) {
        float* dp = H2 + (size_t)d * LATENT + sl * 8;
        float4 v0 = make_float4(acc[0], acc[1], acc[2], acc[3]);
        float4 v1 = make_float4(acc[4], acc[5], acc[6], acc[7]);
        if (init) {
            *(float4*)dp = v0;
            *(float4*)(dp + 4) = v1;
        } else {
            float4 p0 = *(float4*)dp, p1 = *(float4*)(dp + 4);
            *(float4*)dp       = make_float4(p0.x + v0.x, p0.y + v0.y, p0.z + v0.z, p0.w + v0.w);
            *(float4*)(dp + 4) = make_float4(p1.x + v1.x, p1.y + v1.y, p1.z + v1.z, p1.w + v1.w);
        }
    }
}

// ---------------------------------------------------------------------------
// Final prediction: wave per batch element (FINALD == 64 lanes)
// ---------------------------------------------------------------------------
__global__ __launch_bounds__(256)
void predict(const int* __restrict__ uid, const int* __restrict__ iid,
             const float* __restrict__ U, const float* __restrict__ B,
             const float* __restrict__ bu, const float* __restrict__ bb,
             const float* __restrict__ bx, float* __restrict__ out, int batch)
{
    int lane = threadIdx.x & 63, wid = threadIdx.x >> 6;
    int b = blockIdx.x * 4 + wid;
    if (b >= batch) return;
    int u = uid[b], it = iid[b];
    float p = U[(size_t)u * FINALD + lane] * B[(size_t)it * FINALD + lane];
    #pragma unroll
    for (int o = 32; o; o >>= 1) p += __shfl_xor(p, o);
    if (lane == 0) {
        float raw = p + bu[u] + bb[it] + bx[0];
        out[b] = 4.f * (1.f / (1.f + __expf(-raw))) + 1.f;
    }
}

// ---------------------------------------------------------------------------
extern "C" void kernel_launch(void* const* d_in, const int* in_sizes, int n_in,
                              void* d_out, int out_size, void* d_ws, size_t ws_size,
                              hipStream_t stream)
{
    const int N = N_NODES;

    // workspace layout (float units)
    float* ws = (float*)d_ws;
    float* bufA  = ws;                         // 6.4e6 f: H1b (bf16) then H3 (f32)
    float* H2    = ws + 6400000;               // 6.4e6 f
    float* U_all = ws + 12800000;              // 3.2e6 f
    float* B_all = ws + 16000000;              // 3.2e6 f
    float* asf   = ws + 19200000;              // 50000
    float* anb   = asf + N;                    // 50000
    int*   cnt    = (int*)(anb + N);           // 50000
    int*   offs   = cnt + N;                   // 50001
    int*   cursor = offs + N + 1;              // 50000
    int*   csr    = cursor + N;                // 1e6

    unsigned short* H1b = (unsigned short*)bufA;
    float* H3 = bufA;

    dim3 gL(782, 2);   // 50048 rows x 128 cols
    dim3 gF(782, 1);   // 50048 rows x 64 cols
    const int eBlocks = (NEDGE + 255) / 256;

    for (int side = 0; side < 2; ++side) {
        const float* S   = (const float*)d_in[side == 0 ? 2 : 3];
        const int*   edg = (const int*)  d_in[side == 0 ? 4 : 5];
        const float* W1  = (const float*)d_in[side == 0 ? 6 : 10];
        const float* avs = (const float*)d_in[side == 0 ? 7 : 11];
        const float* avn = (const float*)d_in[side == 0 ? 8 : 12];
        const float* om  = (const float*)d_in[side == 0 ? 9 : 13];
        const float* W2a = (const float*)d_in[side == 0 ? 14 : 17];
        const float* W2s = (const float*)d_in[side == 0 ? 15 : 18];
        const float* b2  = (const float*)d_in[side == 0 ? 16 : 19];
        const float* W3  = (const float*)d_in[side == 0 ? 20 : 21];
        const float* H4  = (const float*)d_in[side == 0 ? 22 : 23];
        float* OUT = side == 0 ? U_all : B_all;

        // H1b = bf16( S @ W1 )
        gemm_mfma<<<gL, 256, 0, stream>>>(
            S, W1, IN_DIM, nullptr, nullptr, 0, nullptr, nullptr,
            H1b, N, LATENT, 0, 1);

        rowdots<<<N / 4, 256, 0, stream>>>(H1b, avs, avn, asf, anb, N);

        for (int g = 0; g < NGRAPH; ++g) {
            const int* esrc = edg + (size_t)g * 2 * NEDGE;
            const int* edst = esrc + NEDGE;
            hipMemsetAsync(cnt, 0, (size_t)N * sizeof(int), stream);
            edge_count<<<eBlocks, 256, 0, stream>>>(edst, cnt, NEDGE);
            scan_offsets<<<1, 1024, 0, stream>>>(cnt, offs, cursor, N);
            edge_fill<<<eBlocks, 256, 0, stream>>>(esrc, edst, cursor, csr, NEDGE);
            gat_aggregate<<<N / 4, 256, 0, stream>>>(
                H1b, asf, anb, offs, csr, om, g, g == 0 ? 1 : 0, H2, N);
        }

        // H3 = elu(H2@W2a + S@W2s + b2)   (H3 overlays H1b region)
        gemm_mfma<<<gL, 256, 0, stream>>>(
            H2, W2a, LATENT, S, W2s, IN_DIM, b2, nullptr,
            H3, N, LATENT, 1, 0);

        // OUT = elu(H3@W3) + H4
        gemm_mfma<<<gF, 256, 0, stream>>>(
            H3, W3, LATENT, nullptr, nullptr, 0, nullptr, H4,
            OUT, N, FINALD, 1, 0);
    }

    predict<<<BATCHSZ / 4, 256, 0, stream>>>(
        (const int*)d_in[0], (const int*)d_in[1], U_all, B_all,
        (const float*)d_in[24], (const float*)d_in[25], (const float*)d_in[26],
        (float*)d_out, BATCHSZ);
}

// Round 3
// 884.093 us; speedup vs baseline: 1.9466x; 1.5010x over previous
//
#include <hip/hip_runtime.h>
#include <math.h>

#define N_NODES 50000
#define IN_DIM  256
#define LATENT  128
#define FINALD  64
#define NGRAPH  2
#define NEDGE   1000000
#define BATCHSZ 16384

typedef __attribute__((ext_vector_type(8))) short bf16x8;
typedef __attribute__((ext_vector_type(4))) float f32x4;
typedef __attribute__((ext_vector_type(8))) unsigned short u16x8;
typedef __attribute__((ext_vector_type(4))) unsigned short u16x4;

__device__ inline unsigned short f2bf(float x) {
    unsigned int u = __float_as_uint(x);
    u = (u + 0x7fffu + ((u >> 16) & 1u)) >> 16;
    return (unsigned short)u;
}
__device__ inline float bf2f(unsigned short h) {
    return __uint_as_float(((unsigned int)h) << 16);
}

// ---------------------------------------------------------------------------
// Split-precision bf16 MFMA GEMM (Ah@Bh + Ah@Bl + Al@Bh), 64x64 tile, BK=64.
// ---------------------------------------------------------------------------
#define GBM 64
#define GBK 64

__device__ inline int swz(int r, int k) {
    return r * GBK + ((((k >> 3) ^ (r & 7)) << 3) | (k & 7));
}

__global__ __launch_bounds__(256)
void gemm_mfma(const float* __restrict__ A1, const float* __restrict__ B1, int K1,
               const float* __restrict__ A2, const float* __restrict__ B2, int K2,
               const float* __restrict__ bias, const float* __restrict__ addm,
               void* __restrict__ Cout, int M, int Ncols, int act, int out_bf16)
{
    __shared__ unsigned short AhS[GBM * GBK];
    __shared__ unsigned short AlS[GBM * GBK];
    __shared__ unsigned short BhS[GBM * GBK];
    __shared__ unsigned short BlS[GBM * GBK];

    const int tid = threadIdx.x;
    const int rowBase = blockIdx.x * GBM;
    const int colBase = blockIdx.y * GBM;
    const int wave = tid >> 6, lane = tid & 63;
    const int wr = wave >> 1, wc = wave & 1;
    const int sl = lane & 15, lg = lane >> 4;

    f32x4 acc[2][2] = {};

    const float* Ap = A1;
    const float* Bp = B1;
    int K = K1;

    for (int pass = 0; pass < 2; ++pass) {
        if (pass == 1) { if (!A2) break; Ap = A2; Bp = B2; K = K2; }
        for (int k0 = 0; k0 < K; k0 += GBK) {
            __syncthreads();
            #pragma unroll
            for (int p = 0; p < 4; ++p) {
                int q = p * 256 + tid;
                int row = q >> 4;
                int kq = (q & 15) << 2;
                int grow = rowBase + row;
                float4 v = make_float4(0.f, 0.f, 0.f, 0.f);
                if (grow < M) v = *(const float4*)(Ap + (size_t)grow * K + k0 + kq);
                unsigned short h0 = f2bf(v.x), h1 = f2bf(v.y), h2 = f2bf(v.z), h3 = f2bf(v.w);
                u16x4 hv = {h0, h1, h2, h3};
                u16x4 lv = {f2bf(v.x - bf2f(h0)), f2bf(v.y - bf2f(h1)),
                            f2bf(v.z - bf2f(h2)), f2bf(v.w - bf2f(h3))};
                int off = swz(row, kq);
                *(u16x4*)&AhS[off] = hv;
                *(u16x4*)&AlS[off] = lv;
            }
            {
                int n = tid & 63;
                int kq = (tid >> 6) << 4;
                #pragma unroll
                for (int c = 0; c < 2; ++c) {
                    u16x8 hv, lv;
                    #pragma unroll
                    for (int j = 0; j < 8; ++j) {
                        float x = Bp[(size_t)(k0 + kq + c * 8 + j) * Ncols + colBase + n];
                        unsigned short h = f2bf(x);
                        hv[j] = h;
                        lv[j] = f2bf(x - bf2f(h));
                    }
                    int off = swz(n, kq + c * 8);
                    *(u16x8*)&BhS[off] = hv;
                    *(u16x8*)&BlS[off] = lv;
                }
            }
            __syncthreads();
            #pragma unroll
            for (int ks = 0; ks < 2; ++ks) {
                int kof = ks * 32 + lg * 8;
                bf16x8 ah[2], al[2], bh[2], bl[2];
                #pragma unroll
                for (int f = 0; f < 2; ++f) {
                    int m = wr * 32 + f * 16 + sl;
                    int oa = swz(m, kof);
                    ah[f] = *(const bf16x8*)&AhS[oa];
                    al[f] = *(const bf16x8*)&AlS[oa];
                    int n = wc * 32 + f * 16 + sl;
                    int ob = swz(n, kof);
                    bh[f] = *(const bf16x8*)&BhS[ob];
                    bl[f] = *(const bf16x8*)&BlS[ob];
                }
                #pragma unroll
                for (int fm = 0; fm < 2; ++fm)
                    #pragma unroll
                    for (int fn = 0; fn < 2; ++fn) {
                        acc[fm][fn] = __builtin_amdgcn_mfma_f32_16x16x32_bf16(ah[fm], bh[fn], acc[fm][fn], 0, 0, 0);
                        acc[fm][fn] = __builtin_amdgcn_mfma_f32_16x16x32_bf16(ah[fm], bl[fn], acc[fm][fn], 0, 0, 0);
                        acc[fm][fn] = __builtin_amdgcn_mfma_f32_16x16x32_bf16(al[fm], bh[fn], acc[fm][fn], 0, 0, 0);
                    }
            }
        }
    }

    #pragma unroll
    for (int fm = 0; fm < 2; ++fm)
        #pragma unroll
        for (int r = 0; r < 4; ++r) {
            int row = rowBase + wr * 32 + fm * 16 + lg * 4 + r;
            if (row >= M) continue;
            #pragma unroll
            for (int fn = 0; fn < 2; ++fn) {
                int col = colBase + wc * 32 + fn * 16 + sl;
                float v = acc[fm][fn][r];
                if (bias) v += bias[col];
                if (act) v = v > 0.f ? v : (__expf(v) - 1.f);
                if (addm) v += addm[(size_t)row * Ncols + col];
                if (out_bf16)
                    ((unsigned short*)Cout)[(size_t)row * Ncols + col] = f2bf(v);
                else
                    ((float*)Cout)[(size_t)row * Ncols + col] = v;
            }
        }
}

// ---------------------------------------------------------------------------
// alpha_self / alpha_nb from bf16 H1. Wave per row.
// ---------------------------------------------------------------------------
__global__ __launch_bounds__(256)
void rowdots(const unsigned short* __restrict__ H1b, const float* __restrict__ a1,
             const float* __restrict__ a2,
             float* __restrict__ o1, float* __restrict__ o2, int n)
{
    int lane = threadIdx.x & 63, wid = threadIdx.x >> 6;
    int row = blockIdx.x * 4 + wid;
    if (row >= n) return;
    unsigned int hv = *(const unsigned int*)(H1b + (size_t)row * LATENT + lane * 2);
    float h0 = bf2f((unsigned short)(hv & 0xffffu));
    float h1 = bf2f((unsigned short)(hv >> 16));
    float2 x = *(const float2*)(a1 + lane * 2);
    float2 y = *(const float2*)(a2 + lane * 2);
    float d1 = h0 * x.x + h1 * x.y;
    float d2 = h0 * y.x + h1 * y.y;
    #pragma unroll
    for (int o = 32; o; o >>= 1) {
        d1 += __shfl_xor(d1, o);
        d2 += __shfl_xor(d2, o);
    }
    if (lane == 0) { o1[row] = d1; o2[row] = d2; }
}

// ---------------------------------------------------------------------------
// CSR build, both graphs batched: cnt/offs/cursor are [2][N] concatenated,
// csr is [2e6]. Hierarchical parallel exclusive scan (3 small kernels).
// ---------------------------------------------------------------------------
__global__ void edge_count2(const int* __restrict__ edg, int* __restrict__ cnt, int n)
{
    int g = blockIdx.y;
    const int* dst = edg + (size_t)g * 2 * NEDGE + NEDGE;
    int i = blockIdx.x * blockDim.x + threadIdx.x;
    if (i < NEDGE) atomicAdd(&cnt[g * n + dst[i]], 1);
}

#define SCT 256
#define SCE 4
#define SCCHUNK (SCT * SCE)   // 1024

__global__ __launch_bounds__(SCT)
void scan_partial(const int* __restrict__ cnt, int* __restrict__ bsum, int n)
{
    __shared__ int red[SCT / 64];
    int t = threadIdx.x;
    int base = blockIdx.x * SCCHUNK + t * SCE;
    int s = 0;
    #pragma unroll
    for (int j = 0; j < SCE; ++j) { int i = base + j; if (i < n) s += cnt[i]; }
    #pragma unroll
    for (int o = 32; o; o >>= 1) s += __shfl_xor(s, o);
    int lane = t & 63, w = t >> 6;
    if (lane == 0) red[w] = s;
    __syncthreads();
    if (t == 0) {
        int tot = 0;
        #pragma unroll
        for (int i = 0; i < SCT / 64; ++i) tot += red[i];
        bsum[blockIdx.x] = tot;
    }
}

__global__ __launch_bounds__(128)
void scan_bsum(const int* __restrict__ bsum, int* __restrict__ bbase, int nb)
{
    __shared__ int sm[128];
    int t = threadIdx.x;
    sm[t] = t < nb ? bsum[t] : 0;
    __syncthreads();
    if (t < nb) {
        int acc = 0;
        for (int i = 0; i < t; ++i) acc += sm[i];
        bbase[t] = acc;
    }
}

__global__ __launch_bounds__(SCT)
void scan_fill(const int* __restrict__ cnt, const int* __restrict__ bbase,
               int* __restrict__ offs, int* __restrict__ cursor, int n)
{
    __shared__ int wsum[SCT / 64];
    int t = threadIdx.x;
    int base = blockIdx.x * SCCHUNK + t * SCE;
    int v[SCE];
    int s = 0;
    #pragma unroll
    for (int j = 0; j < SCE; ++j) { int i = base + j; v[j] = (i < n) ? cnt[i] : 0; s += v[j]; }
    // wave inclusive scan
    int lane = t & 63, w = t >> 6;
    int x = s;
    #pragma unroll
    for (int o = 1; o < 64; o <<= 1) {
        int y = __shfl_up(x, o);
        if (lane >= o) x += y;
    }
    if (lane == 63) wsum[w] = x;
    __syncthreads();
    int wbase = 0;
    for (int i = 0; i < w; ++i) wbase += wsum[i];
    int off = bbase[blockIdx.x] + wbase + x - s;   // exclusive prefix
    #pragma unroll
    for (int j = 0; j < SCE; ++j) {
        int i = base + j;
        if (i < n) {
            offs[i] = off; cursor[i] = off;
            off += v[j];
            if (i == n - 1) offs[n] = off;
        }
    }
}

__global__ void edge_fill2(const int* __restrict__ edg, int* __restrict__ cursor,
                           int* __restrict__ csr, int n)
{
    int g = blockIdx.y;
    const int* src = edg + (size_t)g * 2 * NEDGE;
    const int* dst = src + NEDGE;
    int i = blockIdx.x * blockDim.x + threadIdx.x;
    if (i < NEDGE) {
        int d = dst[i];
        int p = atomicAdd(&cursor[g * n + d], 1);
        csr[p] = src[i];
    }
}

// ---------------------------------------------------------------------------
// GAT aggregation, both graphs in one pass. Wave per dst node.
// ---------------------------------------------------------------------------
__global__ __launch_bounds__(256)
void gat_aggregate(const unsigned short* __restrict__ H1b, const float* __restrict__ asf,
                   const float* __restrict__ anb,
                   const int* __restrict__ offs, const int* __restrict__ csr,
                   const float* __restrict__ omega,
                   float* __restrict__ H2, int n)
{
    int lane = threadIdx.x & 63, wid = threadIdx.x >> 6;
    int d = blockIdx.x * 4 + wid;
    if (d >= n) return;
    float ad = asf[d];
    int sub = lane >> 4, sl = lane & 15;
    float acc[8] = {};

    for (int g = 0; g < NGRAPH; ++g) {
        int beg = offs[g * n + d], end = offs[g * n + d + 1];
        float om = omega[g];

        float m = -INFINITY;
        for (int e = beg + lane; e < end; e += 64) {
            float sc = ad + anb[csr[e]];
            sc = sc > 0.f ? sc : 0.2f * sc;
            m = fmaxf(m, sc);
        }
        #pragma unroll
        for (int o = 32; o; o >>= 1) m = fmaxf(m, __shfl_xor(m, o));

        float ss = 0.f;
        for (int e = beg + lane; e < end; e += 64) {
            float sc = ad + anb[csr[e]];
            sc = sc > 0.f ? sc : 0.2f * sc;
            ss += __expf(sc - m);
        }
        #pragma unroll
        for (int o = 32; o; o >>= 1) ss += __shfl_xor(ss, o);
        float wsc = om / (ss + 1e-16f);

        for (int e = beg + sub; e < end; e += 4) {
            int s = csr[e];
            float sc = ad + anb[s];
            sc = sc > 0.f ? sc : 0.2f * sc;
            float w = __expf(sc - m) * wsc;
            u16x8 h = *(const u16x8*)(H1b + (size_t)s * LATENT + sl * 8);
            #pragma unroll
            for (int j = 0; j < 8; ++j) acc[j] += w * bf2f(h[j]);
        }
    }

    #pragma unroll
    for (int j = 0; j < 8; ++j) {
        acc[j] += __shfl_xor(acc[j], 32);
        acc[j] += __shfl_xor(acc[j], 16);
    }
    if (sub == 0) {
        float* dp = H2 + (size_t)d * LATENT + sl * 8;
        *(float4*)dp       = make_float4(acc[0], acc[1], acc[2], acc[3]);
        *(float4*)(dp + 4) = make_float4(acc[4], acc[5], acc[6], acc[7]);
    }
}

// ---------------------------------------------------------------------------
__global__ __launch_bounds__(256)
void predict(const int* __restrict__ uid, const int* __restrict__ iid,
             const float* __restrict__ U, const float* __restrict__ B,
             const float* __restrict__ bu, const float* __restrict__ bb,
             const float* __restrict__ bx, float* __restrict__ out, int batch)
{
    int lane = threadIdx.x & 63, wid = threadIdx.x >> 6;
    int b = blockIdx.x * 4 + wid;
    if (b >= batch) return;
    int u = uid[b], it = iid[b];
    float p = U[(size_t)u * FINALD + lane] * B[(size_t)it * FINALD + lane];
    #pragma unroll
    for (int o = 32; o; o >>= 1) p += __shfl_xor(p, o);
    if (lane == 0) {
        float raw = p + bu[u] + bb[it] + bx[0];
        out[b] = 4.f * (1.f / (1.f + __expf(-raw))) + 1.f;
    }
}

// ---------------------------------------------------------------------------
extern "C" void kernel_launch(void* const* d_in, const int* in_sizes, int n_in,
                              void* d_out, int out_size, void* d_ws, size_t ws_size,
                              hipStream_t stream)
{
    const int N = N_NODES;
    const int N2 = 2 * N;                     // both graphs concatenated

    float* ws = (float*)d_ws;
    float* bufA  = ws;                        // H1b (bf16) then H3 (f32): 6.4e6 f
    float* H2    = ws + 6400000;              // 6.4e6 f
    float* U_all = ws + 12800000;             // 3.2e6 f
    float* B_all = ws + 16000000;             // 3.2e6 f
    float* asf   = ws + 19200000;             // 5e4
    float* anb   = asf + N;                   // 5e4
    int*   cnt    = (int*)(anb + N);          // 2N
    int*   offs   = cnt + N2;                 // 2N+1
    int*   cursor = offs + N2 + 1;            // 2N
    int*   bsum   = cursor + N2;              // 128
    int*   bbase  = bsum + 128;               // 128
    int*   csr    = bbase + 128;              // 2e6

    unsigned short* H1b = (unsigned short*)bufA;
    float* H3 = bufA;

    dim3 gL(782, 2);
    dim3 gF(782, 1);
    dim3 eg((NEDGE + 255) / 256, 2);
    const int scanBlocks = (N2 + SCCHUNK - 1) / SCCHUNK;   // 98

    for (int side = 0; side < 2; ++side) {
        const float* S   = (const float*)d_in[side == 0 ? 2 : 3];
        const int*   edg = (const int*)  d_in[side == 0 ? 4 : 5];
        const float* W1  = (const float*)d_in[side == 0 ? 6 : 10];
        const float* avs = (const float*)d_in[side == 0 ? 7 : 11];
        const float* avn = (const float*)d_in[side == 0 ? 8 : 12];
        const float* om  = (const float*)d_in[side == 0 ? 9 : 13];
        const float* W2a = (const float*)d_in[side == 0 ? 14 : 17];
        const float* W2s = (const float*)d_in[side == 0 ? 15 : 18];
        const float* b2  = (const float*)d_in[side == 0 ? 16 : 19];
        const float* W3  = (const float*)d_in[side == 0 ? 20 : 21];
        const float* H4  = (const float*)d_in[side == 0 ? 22 : 23];
        float* OUT = side == 0 ? U_all : B_all;

        // H1b = bf16( S @ W1 )
        gemm_mfma<<<gL, 256, 0, stream>>>(
            S, W1, IN_DIM, nullptr, nullptr, 0, nullptr, nullptr,
            H1b, N, LATENT, 0, 1);

        rowdots<<<N / 4, 256, 0, stream>>>(H1b, avs, avn, asf, anb, N);

        // batched CSR build for both graphs
        hipMemsetAsync(cnt, 0, (size_t)N2 * sizeof(int), stream);
        edge_count2<<<eg, 256, 0, stream>>>(edg, cnt, N);
        scan_partial<<<scanBlocks, SCT, 0, stream>>>(cnt, bsum, N2);
        scan_bsum<<<1, 128, 0, stream>>>(bsum, bbase, scanBlocks);
        scan_fill<<<scanBlocks, SCT, 0, stream>>>(cnt, bbase, offs, cursor, N2);
        edge_fill2<<<eg, 256, 0, stream>>>(edg, cursor, csr, N);

        // merged 2-graph aggregation
        gat_aggregate<<<N / 4, 256, 0, stream>>>(
            H1b, asf, anb, offs, csr, om, H2, N);

        // H3 = elu(H2@W2a + S@W2s + b2)
        gemm_mfma<<<gL, 256, 0, stream>>>(
            H2, W2a, LATENT, S, W2s, IN_DIM, b2, nullptr,
            H3, N, LATENT, 1, 0);

        // OUT = elu(H3@W3) + H4
        gemm_mfma<<<gF, 256, 0, stream>>>(
            H3, W3, LATENT, nullptr, nullptr, 0, nullptr, H4,
            OUT, N, FINALD, 1, 0);
    }

    predict<<<BATCHSZ / 4, 256, 0, stream>>>(
        (const int*)d_in[0], (const int*)d_in[1], U_all, B_all,
        (const float*)d_in[24], (const float*)d_in[25], (const float*)d_in[26],
        (float*)d_out, BATCHSZ);
}

// Round 4
// 539.981 us; speedup vs baseline: 3.1872x; 1.6373x over previous
//
#include <hip/hip_runtime.h>
#include <math.h>

#define N_NODES 50000
#define IN_DIM  256
#define LATENT  128
#define FINALD  64
#define NGRAPH  2
#define NEDGE   1000000
#define BATCHSZ 16384

#define VN      (2 * N_NODES)          // virtual dst ids (graph-major)
#define NBUCK   ((VN + 255) >> 8)      // 391 buckets of 256 dsts
#define E2      (2 * NEDGE)

typedef __attribute__((ext_vector_type(8))) short bf16x8;
typedef __attribute__((ext_vector_type(4))) float f32x4;
typedef __attribute__((ext_vector_type(8))) unsigned short u16x8;
typedef __attribute__((ext_vector_type(4))) unsigned short u16x4;

__device__ inline unsigned short f2bf(float x) {
    unsigned int u = __float_as_uint(x);
    u = (u + 0x7fffu + ((u >> 16) & 1u)) >> 16;
    return (unsigned short)u;
}
__device__ inline float bf2f(unsigned short h) {
    return __uint_as_float(((unsigned int)h) << 16);
}

// ---------------------------------------------------------------------------
// Split-precision bf16 MFMA GEMM (Ah@Bh + Ah@Bl + Al@Bh), 64x64 tile, BK=64.
// ---------------------------------------------------------------------------
#define GBM 64
#define GBK 64

__device__ inline int swz(int r, int k) {
    return r * GBK + ((((k >> 3) ^ (r & 7)) << 3) | (k & 7));
}

__global__ __launch_bounds__(256)
void gemm_mfma(const float* __restrict__ A1, const float* __restrict__ B1, int K1,
               const float* __restrict__ A2, const float* __restrict__ B2, int K2,
               const float* __restrict__ bias, const float* __restrict__ addm,
               void* __restrict__ Cout, int M, int Ncols, int act, int out_bf16)
{
    __shared__ unsigned short AhS[GBM * GBK];
    __shared__ unsigned short AlS[GBM * GBK];
    __shared__ unsigned short BhS[GBM * GBK];
    __shared__ unsigned short BlS[GBM * GBK];

    const int tid = threadIdx.x;
    const int rowBase = blockIdx.x * GBM;
    const int colBase = blockIdx.y * GBM;
    const int wave = tid >> 6, lane = tid & 63;
    const int wr = wave >> 1, wc = wave & 1;
    const int sl = lane & 15, lg = lane >> 4;

    f32x4 acc[2][2] = {};

    const float* Ap = A1;
    const float* Bp = B1;
    int K = K1;

    for (int pass = 0; pass < 2; ++pass) {
        if (pass == 1) { if (!A2) break; Ap = A2; Bp = B2; K = K2; }
        for (int k0 = 0; k0 < K; k0 += GBK) {
            __syncthreads();
            #pragma unroll
            for (int p = 0; p < 4; ++p) {
                int q = p * 256 + tid;
                int row = q >> 4;
                int kq = (q & 15) << 2;
                int grow = rowBase + row;
                float4 v = make_float4(0.f, 0.f, 0.f, 0.f);
                if (grow < M) v = *(const float4*)(Ap + (size_t)grow * K + k0 + kq);
                unsigned short h0 = f2bf(v.x), h1 = f2bf(v.y), h2 = f2bf(v.z), h3 = f2bf(v.w);
                u16x4 hv = {h0, h1, h2, h3};
                u16x4 lv = {f2bf(v.x - bf2f(h0)), f2bf(v.y - bf2f(h1)),
                            f2bf(v.z - bf2f(h2)), f2bf(v.w - bf2f(h3))};
                int off = swz(row, kq);
                *(u16x4*)&AhS[off] = hv;
                *(u16x4*)&AlS[off] = lv;
            }
            {
                int n = tid & 63;
                int kq = (tid >> 6) << 4;
                #pragma unroll
                for (int c = 0; c < 2; ++c) {
                    u16x8 hv, lv;
                    #pragma unroll
                    for (int j = 0; j < 8; ++j) {
                        float x = Bp[(size_t)(k0 + kq + c * 8 + j) * Ncols + colBase + n];
                        unsigned short h = f2bf(x);
                        hv[j] = h;
                        lv[j] = f2bf(x - bf2f(h));
                    }
                    int off = swz(n, kq + c * 8);
                    *(u16x8*)&BhS[off] = hv;
                    *(u16x8*)&BlS[off] = lv;
                }
            }
            __syncthreads();
            #pragma unroll
            for (int ks = 0; ks < 2; ++ks) {
                int kof = ks * 32 + lg * 8;
                bf16x8 ah[2], al[2], bh[2], bl[2];
                #pragma unroll
                for (int f = 0; f < 2; ++f) {
                    int m = wr * 32 + f * 16 + sl;
                    int oa = swz(m, kof);
                    ah[f] = *(const bf16x8*)&AhS[oa];
                    al[f] = *(const bf16x8*)&AlS[oa];
                    int n = wc * 32 + f * 16 + sl;
                    int ob = swz(n, kof);
                    bh[f] = *(const bf16x8*)&BhS[ob];
                    bl[f] = *(const bf16x8*)&BlS[ob];
                }
                #pragma unroll
                for (int fm = 0; fm < 2; ++fm)
                    #pragma unroll
                    for (int fn = 0; fn < 2; ++fn) {
                        acc[fm][fn] = __builtin_amdgcn_mfma_f32_16x16x32_bf16(ah[fm], bh[fn], acc[fm][fn], 0, 0, 0);
                        acc[fm][fn] = __builtin_amdgcn_mfma_f32_16x16x32_bf16(ah[fm], bl[fn], acc[fm][fn], 0, 0, 0);
                        acc[fm][fn] = __builtin_amdgcn_mfma_f32_16x16x32_bf16(al[fm], bh[fn], acc[fm][fn], 0, 0, 0);
                    }
            }
        }
    }

    #pragma unroll
    for (int fm = 0; fm < 2; ++fm)
        #pragma unroll
        for (int r = 0; r < 4; ++r) {
            int row = rowBase + wr * 32 + fm * 16 + lg * 4 + r;
            if (row >= M) continue;
            #pragma unroll
            for (int fn = 0; fn < 2; ++fn) {
                int col = colBase + wc * 32 + fn * 16 + sl;
                float v = acc[fm][fn][r];
                if (bias) v += bias[col];
                if (act) v = v > 0.f ? v : (__expf(v) - 1.f);
                if (addm) v += addm[(size_t)row * Ncols + col];
                if (out_bf16)
                    ((unsigned short*)Cout)[(size_t)row * Ncols + col] = f2bf(v);
                else
                    ((float*)Cout)[(size_t)row * Ncols + col] = v;
            }
        }
}

// ---------------------------------------------------------------------------
// alpha_self / alpha_nb from bf16 H1. Wave per row.
// ---------------------------------------------------------------------------
__global__ __launch_bounds__(256)
void rowdots(const unsigned short* __restrict__ H1b, const float* __restrict__ a1,
             const float* __restrict__ a2,
             float* __restrict__ o1, float* __restrict__ o2, int n)
{
    int lane = threadIdx.x & 63, wid = threadIdx.x >> 6;
    int row = blockIdx.x * 4 + wid;
    if (row >= n) return;
    unsigned int hv = *(const unsigned int*)(H1b + (size_t)row * LATENT + lane * 2);
    float h0 = bf2f((unsigned short)(hv & 0xffffu));
    float h1 = bf2f((unsigned short)(hv >> 16));
    float2 x = *(const float2*)(a1 + lane * 2);
    float2 y = *(const float2*)(a2 + lane * 2);
    float d1 = h0 * x.x + h1 * x.y;
    float d2 = h0 * y.x + h1 * y.y;
    #pragma unroll
    for (int o = 32; o; o >>= 1) {
        d1 += __shfl_xor(d1, o);
        d2 += __shfl_xor(d2, o);
    }
    if (lane == 0) { o1[row] = d1; o2[row] = d2; }
}

// ---------------------------------------------------------------------------
// Bucketed counting sort of edges by virtual dst (vd = g*N + dst).
// 391 buckets x 256 dsts. No global per-dst atomics; LDS-local everything.
// ---------------------------------------------------------------------------
__global__ __launch_bounds__(256)
void bucket_hist(const int* __restrict__ edg, int* __restrict__ bhist)
{
    __shared__ int h[NBUCK];
    int tid = threadIdx.x;
    for (int i = tid; i < NBUCK; i += 256) h[i] = 0;
    __syncthreads();
    int g = blockIdx.y;
    const int* dst = edg + (size_t)g * E2 + NEDGE;
    for (int i = blockIdx.x * 256 + tid; i < NEDGE; i += gridDim.x * 256)
        atomicAdd(&h[(g * N_NODES + dst[i]) >> 8], 1);
    __syncthreads();
    for (int i = tid; i < NBUCK; i += 256)
        if (h[i]) atomicAdd(&bhist[i], h[i]);
}

__global__ __launch_bounds__(512)
void bucket_scan(const int* __restrict__ bhist, int* __restrict__ bbase,
                 int* __restrict__ bcursor, int* __restrict__ offs)
{
    __shared__ int sm[512];
    int t = threadIdx.x;
    sm[t] = (t < NBUCK) ? bhist[t] : 0;
    __syncthreads();
    for (int o = 1; o < 512; o <<= 1) {
        int v = sm[t];
        if (t >= o) v += sm[t - o];
        __syncthreads();
        sm[t] = v;
        __syncthreads();
    }
    if (t < NBUCK) { bbase[t + 1] = sm[t]; bcursor[t] = 0; }
    if (t == 0) { bbase[0] = 0; offs[VN] = E2; }
}

__global__ __launch_bounds__(256)
void partition_edges(const int* __restrict__ edg, const int* __restrict__ bbase,
                     int* __restrict__ bcursor, int* __restrict__ ebuf)
{
    __shared__ int bh[NBUCK];
    __shared__ int lbase[NBUCK];
    __shared__ int lcur[NBUCK];
    int tid = threadIdx.x;
    const int CH = (E2 + 255) / 256;          // 7813
    int start = blockIdx.x * CH;
    int stop  = min(start + CH, E2);

    for (int i = tid; i < NBUCK; i += 256) bh[i] = 0;
    __syncthreads();
    for (int i = start + tid; i < stop; i += 256) {
        int g = i >= NEDGE;
        int idx = i - (g ? NEDGE : 0);
        int dst = edg[(size_t)g * E2 + NEDGE + idx];
        atomicAdd(&bh[(g * N_NODES + dst) >> 8], 1);
    }
    __syncthreads();
    for (int i = tid; i < NBUCK; i += 256) {
        int c = bh[i];
        lbase[i] = c > 0 ? bbase[i] + atomicAdd(&bcursor[i], c) : 0;
        lcur[i] = 0;
    }
    __syncthreads();
    for (int i = start + tid; i < stop; i += 256) {
        int g = i >= NEDGE;
        int idx = i - (g ? NEDGE : 0);
        int src = edg[(size_t)g * E2 + idx];
        int dst = edg[(size_t)g * E2 + NEDGE + idx];
        int vd = g * N_NODES + dst;
        int b = vd >> 8;
        int p = lbase[b] + atomicAdd(&lcur[b], 1);
        ebuf[p] = ((vd & 255) << 16) | src;
    }
}

__global__ __launch_bounds__(256)
void bucket_csr(const int* __restrict__ ebuf, const int* __restrict__ bbase,
                int* __restrict__ offs, unsigned short* __restrict__ csr)
{
    __shared__ int cnt[256];
    __shared__ int excl[256];
    __shared__ int cur[256];
    __shared__ int wsum[4];
    int tid = threadIdx.x;
    int b = blockIdx.x;
    int lo = bbase[b], hi = bbase[b + 1];

    cnt[tid] = 0; cur[tid] = 0;
    __syncthreads();
    for (int i = lo + tid; i < hi; i += 256)
        atomicAdd(&cnt[ebuf[i] >> 16], 1);
    __syncthreads();

    int lane = tid & 63, w = tid >> 6;
    int v = cnt[tid];
    int x = v;
    #pragma unroll
    for (int o = 1; o < 64; o <<= 1) {
        int y = __shfl_up(x, o);
        if (lane >= o) x += y;
    }
    if (lane == 63) wsum[w] = x;
    __syncthreads();
    int wb = 0;
    for (int i = 0; i < w; ++i) wb += wsum[i];
    int ex = wb + x - v;
    excl[tid] = ex;
    int vd = b * 256 + tid;
    if (vd < VN) offs[vd] = lo + ex;
    __syncthreads();

    for (int i = lo + tid; i < hi; i += 256) {
        int e = ebuf[i];
        int dl = e >> 16;
        int p = excl[dl] + atomicAdd(&cur[dl], 1);
        csr[lo + p] = (unsigned short)(e & 0xFFFF);
    }
}

// ---------------------------------------------------------------------------
// GAT aggregation, both graphs in one pass. Wave per dst node.
// ---------------------------------------------------------------------------
__global__ __launch_bounds__(256)
void gat_aggregate(const unsigned short* __restrict__ H1b, const float* __restrict__ asf,
                   const float* __restrict__ anb,
                   const int* __restrict__ offs, const unsigned short* __restrict__ csr,
                   const float* __restrict__ omega,
                   float* __restrict__ H2, int n)
{
    int lane = threadIdx.x & 63, wid = threadIdx.x >> 6;
    int d = blockIdx.x * 4 + wid;
    if (d >= n) return;
    float ad = asf[d];
    int sub = lane >> 4, sl = lane & 15;
    float acc[8] = {};

    for (int g = 0; g < NGRAPH; ++g) {
        int beg = offs[g * n + d], end = offs[g * n + d + 1];
        float om = omega[g];

        float m = -INFINITY;
        for (int e = beg + lane; e < end; e += 64) {
            float sc = ad + anb[csr[e]];
            sc = sc > 0.f ? sc : 0.2f * sc;
            m = fmaxf(m, sc);
        }
        #pragma unroll
        for (int o = 32; o; o >>= 1) m = fmaxf(m, __shfl_xor(m, o));

        float ss = 0.f;
        for (int e = beg + lane; e < end; e += 64) {
            float sc = ad + anb[csr[e]];
            sc = sc > 0.f ? sc : 0.2f * sc;
            ss += __expf(sc - m);
        }
        #pragma unroll
        for (int o = 32; o; o >>= 1) ss += __shfl_xor(ss, o);
        float wsc = om / (ss + 1e-16f);

        for (int e = beg + sub; e < end; e += 4) {
            int s = csr[e];
            float sc = ad + anb[s];
            sc = sc > 0.f ? sc : 0.2f * sc;
            float w = __expf(sc - m) * wsc;
            u16x8 h = *(const u16x8*)(H1b + (size_t)s * LATENT + sl * 8);
            #pragma unroll
            for (int j = 0; j < 8; ++j) acc[j] += w * bf2f(h[j]);
        }
    }

    #pragma unroll
    for (int j = 0; j < 8; ++j) {
        acc[j] += __shfl_xor(acc[j], 32);
        acc[j] += __shfl_xor(acc[j], 16);
    }
    if (sub == 0) {
        float* dp = H2 + (size_t)d * LATENT + sl * 8;
        *(float4*)dp       = make_float4(acc[0], acc[1], acc[2], acc[3]);
        *(float4*)(dp + 4) = make_float4(acc[4], acc[5], acc[6], acc[7]);
    }
}

// ---------------------------------------------------------------------------
__global__ __launch_bounds__(256)
void predict(const int* __restrict__ uid, const int* __restrict__ iid,
             const float* __restrict__ U, const float* __restrict__ B,
             const float* __restrict__ bu, const float* __restrict__ bb,
             const float* __restrict__ bx, float* __restrict__ out, int batch)
{
    int lane = threadIdx.x & 63, wid = threadIdx.x >> 6;
    int b = blockIdx.x * 4 + wid;
    if (b >= batch) return;
    int u = uid[b], it = iid[b];
    float p = U[(size_t)u * FINALD + lane] * B[(size_t)it * FINALD + lane];
    #pragma unroll
    for (int o = 32; o; o >>= 1) p += __shfl_xor(p, o);
    if (lane == 0) {
        float raw = p + bu[u] + bb[it] + bx[0];
        out[b] = 4.f * (1.f / (1.f + __expf(-raw))) + 1.f;
    }
}

// ---------------------------------------------------------------------------
extern "C" void kernel_launch(void* const* d_in, const int* in_sizes, int n_in,
                              void* d_out, int out_size, void* d_ws, size_t ws_size,
                              hipStream_t stream)
{
    const int N = N_NODES;

    float* ws = (float*)d_ws;
    float* bufA  = ws;                        // H1b (bf16) then H3 (f32): 6.4e6 f
    float* H2    = ws + 6400000;              // 6.4e6 f  (ebuf overlays this)
    float* U_all = ws + 12800000;             // 3.2e6 f
    float* B_all = ws + 16000000;             // 3.2e6 f
    float* asf   = ws + 19200000;             // 5e4
    float* anb   = asf + N;                   // 5e4
    int*   offs    = (int*)(anb + N);         // VN+1
    int*   bhist   = offs + VN + 1;           // NBUCK
    int*   bbase   = bhist + NBUCK;           // NBUCK+1
    int*   bcursor = bbase + NBUCK + 1;       // NBUCK
    unsigned short* csr = (unsigned short*)(bcursor + NBUCK);  // E2 ushorts
    int*   ebuf  = (int*)H2;                  // E2 ints, dead before gat writes H2

    unsigned short* H1b = (unsigned short*)bufA;
    float* H3 = bufA;

    dim3 gL(782, 2);
    dim3 gF(782, 1);
    dim3 hg(256, 2);

    for (int side = 0; side < 2; ++side) {
        const float* S   = (const float*)d_in[side == 0 ? 2 : 3];
        const int*   edg = (const int*)  d_in[side == 0 ? 4 : 5];
        const float* W1  = (const float*)d_in[side == 0 ? 6 : 10];
        const float* avs = (const float*)d_in[side == 0 ? 7 : 11];
        const float* avn = (const float*)d_in[side == 0 ? 8 : 12];
        const float* om  = (const float*)d_in[side == 0 ? 9 : 13];
        const float* W2a = (const float*)d_in[side == 0 ? 14 : 17];
        const float* W2s = (const float*)d_in[side == 0 ? 15 : 18];
        const float* b2  = (const float*)d_in[side == 0 ? 16 : 19];
        const float* W3  = (const float*)d_in[side == 0 ? 20 : 21];
        const float* H4  = (const float*)d_in[side == 0 ? 22 : 23];
        float* OUT = side == 0 ? U_all : B_all;

        // H1b = bf16( S @ W1 )
        gemm_mfma<<<gL, 256, 0, stream>>>(
            S, W1, IN_DIM, nullptr, nullptr, 0, nullptr, nullptr,
            H1b, N, LATENT, 0, 1);

        rowdots<<<N / 4, 256, 0, stream>>>(H1b, avs, avn, asf, anb, N);

        // bucketed CSR build for both graphs
        hipMemsetAsync(bhist, 0, NBUCK * sizeof(int), stream);
        bucket_hist<<<hg, 256, 0, stream>>>(edg, bhist);
        bucket_scan<<<1, 512, 0, stream>>>(bhist, bbase, bcursor, offs);
        partition_edges<<<256, 256, 0, stream>>>(edg, bbase, bcursor, ebuf);
        bucket_csr<<<NBUCK, 256, 0, stream>>>(ebuf, bbase, offs, csr);

        // merged 2-graph aggregation
        gat_aggregate<<<N / 4, 256, 0, stream>>>(
            H1b, asf, anb, offs, csr, om, H2, N);

        // H3 = elu(H2@W2a + S@W2s + b2)
        gemm_mfma<<<gL, 256, 0, stream>>>(
            H2, W2a, LATENT, S, W2s, IN_DIM, b2, nullptr,
            H3, N, LATENT, 1, 0);

        // OUT = elu(H3@W3) + H4
        gemm_mfma<<<gF, 256, 0, stream>>>(
            H3, W3, LATENT, nullptr, nullptr, 0, nullptr, H4,
            OUT, N, FINALD, 1, 0);
    }

    predict<<<BATCHSZ / 4, 256, 0, stream>>>(
        (const int*)d_in[0], (const int*)d_in[1], U_all, B_all,
        (const float*)d_in[24], (const float*)d_in[25], (const float*)d_in[26],
        (float*)d_out, BATCHSZ);
}